// Round 1
// baseline (81.651 us; speedup 1.0000x reference)
//
#include <hip/hip_runtime.h>

#define BB 64
#define NN 64
#define TT 100
#define WV 16                 // waves per block (1024 threads)
#define SP (BB + 1)           // padded LDS stride: breaks t-stride bank alias

// Single fused kernel: block = one n, 16 waves. All (b,t) positions for this n
// staged in LDS (52 KB), each wave sweeps t = w, w+16, ... and accumulates its
// per-b partial loss in a register; cross-wave combine in LDS; direct out
// write. Eliminates the 400 KB ws round-trip, the 16-block reduce kernel
// (pure tail), and one launch. Phase-2 math is identical to the verified R6
// path: min-only difference-form d2 from wave-uniform LDS broadcast; drop
// lane uses the exact reference sq-form via shfl.
__global__ __launch_bounds__(1024) void social_fused_kernel(
    const float* __restrict__ x,          // (B, N, T, 6) f32
    const float* __restrict__ wfa,        // (B, 3, 3)    f32
    const int* __restrict__ rand_idx,     // (T*N, B)     i32 in [0, B-2]
    const int* __restrict__ drop_mask,    // (T*N, B)     bool as i32
    float* __restrict__ out)              // (B, N)
{
    const int n   = blockIdx.x;           // grid = 64 blocks
    const int tid = threadIdx.x;

    __shared__ float2 S[TT * SP];         // S[t*SP + b] = (gx, gy)
    __shared__ float  Rld[WV][BB];

    // ---- phase 1: load + transform all (b, t) for this n ----
    {
        const int lb = tid >> 4;          // 0..63 agent
        const int k  = tid & 15;          // 0..15 t-phase
        const float* wp = wfa + lb * 9;
        const float r00 = wp[0], r01 = wp[1], tx = wp[2];
        const float r10 = wp[3], r11 = wp[4], ty = wp[5];
        const size_t xb = (((size_t)lb * NN + n) * (size_t)TT) * 6;
        #pragma unroll
        for (int j = 0; j < 7; ++j) {
            const int t = k + 16 * j;     // covers 0..99 (k<4 does a 7th)
            if (t < TT) {
                const float2 p = *(const float2*)(x + xb + (size_t)t * 6);
                const float gx = r00 * p.x + r01 * p.y + tx;
                const float gy = r10 * p.x + r11 * p.y + ty;
                S[t * SP + lb] = make_float2(gx, gy);
            }
        }
    }
    __syncthreads();

    // ---- phase 2: wave w sweeps slices t = w, w+16, ... ----
    const int w = tid >> 6;
    const int b = tid & 63;
    const float INF = __int_as_float(0x7f800000);

    float acc = 0.f;
    for (int t = w; t < TT; t += WV) {
        const int s = t * NN + n;
        const size_t sb = (size_t)s * BB + b;
        const int r  = rand_idx[sb];      // coalesced, issued early
        const int dm = drop_mask[sb];

        const float2* St = S + t * SP;    // wave-uniform base for this slice
        const float2 g = St[b];           // 2 lanes/bank: free
        const float gx = g.x, gy = g.y;

        // min over c != b of (gx-qx)^2 + (gy-qy)^2; 4 independent chains.
        float m0 = INF, m1 = INF, m2 = INF, m3 = INF;
        #pragma unroll
        for (int i = 0; i < 16; ++i) {
            {
                const int c = i;
                const float2 q = St[c];   // wave-uniform addr -> broadcast
                const float dx = gx - q.x, dy = gy - q.y;
                float d2 = fmaf(dx, dx, dy * dy);
                d2 = (c == b) ? INF : d2;
                m0 = fminf(m0, d2);
            }
            {
                const int c = 16 + i;
                const float2 q = St[c];
                const float dx = gx - q.x, dy = gy - q.y;
                float d2 = fmaf(dx, dx, dy * dy);
                d2 = (c == b) ? INF : d2;
                m1 = fminf(m1, d2);
            }
            {
                const int c = 32 + i;
                const float2 q = St[c];
                const float dx = gx - q.x, dy = gy - q.y;
                float d2 = fmaf(dx, dx, dy * dy);
                d2 = (c == b) ? INF : d2;
                m2 = fminf(m2, d2);
            }
            {
                const int c = 48 + i;
                const float2 q = St[c];
                const float dx = gx - q.x, dy = gy - q.y;
                float d2 = fmaf(dx, dx, dy * dy);
                d2 = (c == b) ? INF : d2;
                m3 = fminf(m3, d2);
            }
        }
        const float best = fminf(fminf(m0, m1), fminf(m2, m3));

        // drop-lane neighbor distance: reference sq-form via shfl (exact path)
        const int rnb = r + (r >= b ? 1 : 0);   // skip-self remap, never == b
        const float sq  = fmaf(gx, gx, gy * gy);
        const float qx  = __shfl(gx, rnb);
        const float qy  = __shfl(gy, rnb);
        const float qsq = __shfl(sq, rnb);
        const float d2r = fmaf(-2.0f, fmaf(gx, qx, gy * qy), sq + qsq);

        const float d2sel = dm ? d2r : best;
        const float nd = sqrtf(fmaxf(d2sel, 1e-12f));
        const float diff = nd - 1.5f;
        acc += diff * diff;
    }
    Rld[w][b] = acc;
    __syncthreads();

    // ---- phase 3: cross-wave combine, direct out write ----
    if (w == 0) {
        float ssum = 0.f;
        #pragma unroll
        for (int jj = 0; jj < WV; ++jj)
            ssum += Rld[jj][b];           // banks 2-way: free
        out[(size_t)b * NN + n] = ssum * (1.0f / TT);
    }
}

extern "C" void kernel_launch(void* const* d_in, const int* in_sizes, int n_in,
                              void* d_out, int out_size, void* d_ws, size_t ws_size,
                              hipStream_t stream) {
    const float* x = (const float*)d_in[0];
    const float* wfa = (const float*)d_in[1];
    const int* rand_idx = (const int*)d_in[2];
    const int* drop_mask = (const int*)d_in[3];
    float* out = (float*)d_out;
    (void)d_ws; (void)ws_size;            // no workspace needed anymore

    social_fused_kernel<<<NN, 1024, 0, stream>>>(x, wfa, rand_idx, drop_mask, out);
}

// Round 2
// 69.792 us; speedup vs baseline: 1.1699x; 1.1699x over previous
//
#include <hip/hip_runtime.h>

#define BB 64
#define NN 64
#define TT 100
#define WV 16                 // waves per block (1024 threads)
#define SP (BB + 1)           // padded LDS stride: breaks t-stride bank alias

// Single fused kernel, full-chip spread: grid = 256 blocks = (n, b-quarter).
// Round-1 post-mortem: 64 blocks pinned all compute on 64 CUs (+11 us, matched
// 5.7M SIMD-cyc / 256 SIMDs arithmetic). Splitting b across 4 blocks per n
// restores 256-CU spread (4096 waves) while keeping ONE dispatch, no ws, no
// reduce kernel. Phase-1 staging is duplicated 4x per n (L2-hot, ~negligible).
// Wave layout in phase 2: 64 lanes = 4 t-slices x 16 b; 2 iterations cover
// t = w*4+tq and 64 + w*4+tq (masked at t>=100).
// Inner min loop identical to the verified path (difference-form d2, LDS
// broadcast, 4 ILP chains). Drop-lane neighbor read from LDS (wave no longer
// holds all 64 b): qsq = fmaf(qx,qx,qy*qy) is bit-identical to the former
// __shfl(sq) since S holds the exact register values.
__global__ __launch_bounds__(1024) void social_fused_kernel(
    const float* __restrict__ x,          // (B, N, T, 6) f32
    const float* __restrict__ wfa,        // (B, 3, 3)    f32
    const int* __restrict__ rand_idx,     // (T*N, B)     i32 in [0, B-2]
    const int* __restrict__ drop_mask,    // (T*N, B)     bool as i32
    float* __restrict__ out)              // (B, N)
{
    const int n   = blockIdx.x & 63;
    const int bq  = blockIdx.x >> 6;      // 0..3: this block owns b in [16bq, 16bq+16)
    const int tid = threadIdx.x;

    __shared__ float2 S[TT * SP];         // S[t*SP + c] = (gx, gy)
    __shared__ float  Rw[WV][16];

    // ---- phase 1: load + transform all (agent, t) for this n ----
    {
        const int lb = tid >> 4;          // 0..63 agent
        const int k  = tid & 15;          // 0..15 t-phase
        const float* wp = wfa + lb * 9;
        const float r00 = wp[0], r01 = wp[1], tx = wp[2];
        const float r10 = wp[3], r11 = wp[4], ty = wp[5];
        const size_t xb = (((size_t)lb * NN + n) * (size_t)TT) * 6;
        #pragma unroll
        for (int j = 0; j < 7; ++j) {
            const int t = k + 16 * j;     // covers 0..99
            if (t < TT) {
                const float2 p = *(const float2*)(x + xb + (size_t)t * 6);
                const float gx = r00 * p.x + r01 * p.y + tx;
                const float gy = r10 * p.x + r11 * p.y + ty;
                S[t * SP + lb] = make_float2(gx, gy);
            }
        }
    }
    __syncthreads();

    // ---- phase 2: wave w, lanes = (tq 0..3) x (bl 0..15) ----
    const int w  = tid >> 6;              // 0..15
    const int ln = tid & 63;
    const int tq = ln >> 4;               // 0..3
    const int bl = ln & 15;               // 0..15
    const int b  = bq * 16 + bl;

    const float INF = __int_as_float(0x7f800000);
    float acc = 0.f;

    #pragma unroll
    for (int it = 0; it < 2; ++it) {
        const int t = it * 64 + w * 4 + tq;   // it0: 0..63, it1: 64..127 masked
        if (t < TT) {
            const size_t sb = (size_t)(t * NN + n) * BB + b;
            const int r  = rand_idx[sb];      // coalesced per t-group
            const int dm = drop_mask[sb];

            const float2* St = S + t * SP;
            const float2 g = St[b];
            const float gx = g.x, gy = g.y;

            // min over c != b; 4 independent chains; 4-addr LDS broadcast
            float m0 = INF, m1 = INF, m2 = INF, m3 = INF;
            #pragma unroll
            for (int i = 0; i < 16; ++i) {
                {
                    const int c = i;
                    const float2 q = St[c];
                    const float dx = gx - q.x, dy = gy - q.y;
                    float d2 = fmaf(dx, dx, dy * dy);
                    d2 = (c == b) ? INF : d2;
                    m0 = fminf(m0, d2);
                }
                {
                    const int c = 16 + i;
                    const float2 q = St[c];
                    const float dx = gx - q.x, dy = gy - q.y;
                    float d2 = fmaf(dx, dx, dy * dy);
                    d2 = (c == b) ? INF : d2;
                    m1 = fminf(m1, d2);
                }
                {
                    const int c = 32 + i;
                    const float2 q = St[c];
                    const float dx = gx - q.x, dy = gy - q.y;
                    float d2 = fmaf(dx, dx, dy * dy);
                    d2 = (c == b) ? INF : d2;
                    m2 = fminf(m2, d2);
                }
                {
                    const int c = 48 + i;
                    const float2 q = St[c];
                    const float dx = gx - q.x, dy = gy - q.y;
                    float d2 = fmaf(dx, dx, dy * dy);
                    d2 = (c == b) ? INF : d2;
                    m3 = fminf(m3, d2);
                }
            }
            const float best = fminf(fminf(m0, m1), fminf(m2, m3));

            // drop-lane neighbor: exact reference sq-form, neighbor from LDS
            const int rnb = r + (r >= b ? 1 : 0);   // skip-self remap
            const float sq  = fmaf(gx, gx, gy * gy);
            const float2 qn = St[rnb];
            const float qsq = fmaf(qn.x, qn.x, qn.y * qn.y);
            const float d2r = fmaf(-2.0f, fmaf(gx, qn.x, gy * qn.y), sq + qsq);

            const float d2sel = dm ? d2r : best;
            const float nd = sqrtf(fmaxf(d2sel, 1e-12f));
            const float diff = nd - 1.5f;
            acc += diff * diff;
        }
    }

    // ---- phase 3: reduce over tq lanes, then over waves; direct out ----
    acc += __shfl_down(acc, 32);
    acc += __shfl_down(acc, 16);          // lanes 0..15 hold per-bl sums
    if (ln < 16) Rw[w][ln] = acc;
    __syncthreads();

    if (tid < 16) {
        float ssum = 0.f;
        #pragma unroll
        for (int jj = 0; jj < WV; ++jj)
            ssum += Rw[jj][tid];
        out[(size_t)(bq * 16 + tid) * NN + n] = ssum * (1.0f / TT);
    }
}

extern "C" void kernel_launch(void* const* d_in, const int* in_sizes, int n_in,
                              void* d_out, int out_size, void* d_ws, size_t ws_size,
                              hipStream_t stream) {
    const float* x = (const float*)d_in[0];
    const float* wfa = (const float*)d_in[1];
    const int* rand_idx = (const int*)d_in[2];
    const int* drop_mask = (const int*)d_in[3];
    float* out = (float*)d_out;
    (void)d_ws; (void)ws_size;            // no workspace needed

    social_fused_kernel<<<NN * 4, 1024, 0, stream>>>(
        x, wfa, rand_idx, drop_mask, out);
}